// Round 12
// baseline (830.375 us; speedup 1.0000x reference)
//
#include <hip/hip_runtime.h>

#define PAD 64
#define NSLOT 64   // stats scatter slots (contention spreading)

// ---------------- init: zero cnt + stats (blocks 0..255) | bilinear M2 (block 256) ----------------
__global__ __launch_bounds__(256) void init_kernel(int* __restrict__ cnt, float* __restrict__ stats,
                                                   int n, int nstat,
                                                   const float* __restrict__ p1,
                                                   const float* __restrict__ p2,
                                                   float* __restrict__ M2) {
  if (blockIdx.x < 256) {
    int i = blockIdx.x * 256 + threadIdx.x;
    int stride = 256 * 256;
    for (int j = i; j < n; j += stride) cnt[j] = 0;
    for (int j = i; j < nstat; j += stride) stats[j] = 0.f;
    return;
  }
  // single block: M2 = (p1 @ p2) @ p1^T
  __shared__ float Mtmp[128 * 128];
  __shared__ float prow[2 * 128];
  int tid = threadIdx.x;
  int jj = tid & 127;
  int ii = tid >> 7;
  for (int ip = 0; ip < 64; ++ip) {
    __syncthreads();
    prow[tid] = p1[(2 * ip + ii) * 128 + jj];
    __syncthreads();
    float acc = 0.f;
    const float* pr = &prow[ii * 128];
#pragma unroll 4
    for (int k = 0; k < 128; ++k) acc = fmaf(pr[k], p2[k * 128 + jj], acc);
    Mtmp[(2 * ip + ii) * 128 + jj] = acc;
  }
  __syncthreads();
  for (int ip = 0; ip < 64; ++ip) {
    int i = 2 * ip + ii;
    const float* mr = &Mtmp[i * 128];
    const float* pj = p1 + (size_t)jj * 128;
    float acc = 0.f;
#pragma unroll 4
    for (int l = 0; l < 128; ++l) acc = fmaf(mr[l], pj[l], acc);
    M2[i * 128 + jj] = acc;
  }
}

// ---------------- fused degree count + padded-CSR fill ----------------
__global__ void fillcsr_kernel(const int* __restrict__ row, const int* __restrict__ col,
                               int* __restrict__ cnt, int* __restrict__ csr, int ne) {
  int e = blockIdx.x * blockDim.x + threadIdx.x;
  if (e < ne) {
    int d = col[e];
    int p = atomicAdd(&cnt[d], 1);
    if (p < PAD) csr[d * PAD + p] = row[e];
  }
}

// ---------------- GEMM: out[row] = dis[row] * ( leaky(BN(A[row])) @ W + b ) ----------------
// K-paneled (4 panels of 32): 33 KB LDS -> 4 blocks/CU. k-major A panel, ds_read_b128 inner loop.
__global__ __launch_bounds__(256, 4) void gemm_kernel(
    const float* __restrict__ A, const float* __restrict__ W, const float* __restrict__ bias,
    float* __restrict__ out, int n, float invN,
    const float* __restrict__ bn_sum, const float* __restrict__ bn_sq,
    const float* __restrict__ bn_g, const float* __restrict__ bn_b, int use_bn,
    const int* __restrict__ cnt) {
  __shared__ float Ws[32 * 128];    // Ws[k][col], k local to panel
  __shared__ float xs[32 * 128];    // xs[k][row], k local to panel
  __shared__ float bnsc[128], bnsh[128];
  int tid = threadIdx.x;
  if (tid < 128) {
    if (use_bn) {
      float s = 0.f, q = 0.f;
      for (int r2 = 0; r2 < NSLOT; ++r2) { s += bn_sum[r2 * 128 + tid]; q += bn_sq[r2 * 128 + tid]; }
      float m = s * invN;
      float var = q * invN - m * m;
      float rs = rsqrtf(var + 1e-5f);
      float sc = rs * bn_g[tid];
      bnsc[tid] = sc;
      bnsh[tid] = bn_b[tid] - m * sc;
    } else {
      bnsc[tid] = 1.f; bnsh[tid] = 0.f;
    }
  }
  int base = blockIdx.x * 128;
  int tx = tid & 15, ty = tid >> 4;
  int c0 = tx * 4, r0 = ty * 4;
  int r = tid & 127;            // staging row
  int row_s = base + r;
  int hf = tid >> 7;            // 0/1
  int kw = tid >> 5;            // 0..7 (W staging k)
  int c4 = tid & 31;            // W staging col4
  const float4* Arow = (const float4*)(A + (size_t)row_s * 128);
  float acc[8][8];
#pragma unroll
  for (int i = 0; i < 8; ++i)
#pragma unroll
    for (int j = 0; j < 8; ++j) acc[i][j] = 0.f;

  for (int kp = 0; kp < 4; ++kp) {
    __syncthreads();
#pragma unroll
    for (int it = 0; it < 4; ++it) {
      int kl = kw + it * 8;
      float4 wv = ((const float4*)(W + (size_t)(kp * 32 + kl) * 128))[c4];
      *(float4*)&Ws[kl * 128 + c4 * 4] = wv;
    }
#pragma unroll
    for (int it = 0; it < 4; ++it) {
      int kbl = hf + it * 2;
      float4 v = make_float4(0.f, 0.f, 0.f, 0.f);
      if (row_s < n) v = Arow[kp * 8 + kbl];
      if (use_bn) {
        int k0 = kp * 32 + kbl * 4;
        float t;
        t = v.x * bnsc[k0 + 0] + bnsh[k0 + 0]; v.x = t >= 0.f ? t : 0.1f * t;
        t = v.y * bnsc[k0 + 1] + bnsh[k0 + 1]; v.y = t >= 0.f ? t : 0.1f * t;
        t = v.z * bnsc[k0 + 2] + bnsh[k0 + 2]; v.z = t >= 0.f ? t : 0.1f * t;
        t = v.w * bnsc[k0 + 3] + bnsh[k0 + 3]; v.w = t >= 0.f ? t : 0.1f * t;
      }
      int kl = kbl * 4;
      xs[(kl + 0) * 128 + r] = v.x;
      xs[(kl + 1) * 128 + r] = v.y;
      xs[(kl + 2) * 128 + r] = v.z;
      xs[(kl + 3) * 128 + r] = v.w;
    }
    __syncthreads();
#pragma unroll 4
    for (int k = 0; k < 32; ++k) {
      float4 a0 = *(const float4*)&xs[k * 128 + r0];
      float4 a1 = *(const float4*)&xs[k * 128 + 64 + r0];
      float4 w0 = *(const float4*)&Ws[k * 128 + c0];
      float4 w1 = *(const float4*)&Ws[k * 128 + 64 + c0];
      float xr[8], wc[8];
      xr[0] = a0.x; xr[1] = a0.y; xr[2] = a0.z; xr[3] = a0.w;
      xr[4] = a1.x; xr[5] = a1.y; xr[6] = a1.z; xr[7] = a1.w;
      wc[0] = w0.x; wc[1] = w0.y; wc[2] = w0.z; wc[3] = w0.w;
      wc[4] = w1.x; wc[5] = w1.y; wc[6] = w1.z; wc[7] = w1.w;
#pragma unroll
      for (int i = 0; i < 8; ++i)
#pragma unroll
        for (int j = 0; j < 8; ++j)
          acc[i][j] = fmaf(xr[i], wc[j], acc[i][j]);
    }
  }
  float bb0[4], bb1[4];
#pragma unroll
  for (int j = 0; j < 4; ++j) { bb0[j] = bias[c0 + j]; bb1[j] = bias[64 + c0 + j]; }
#pragma unroll
  for (int i = 0; i < 8; ++i) {
    int row = base + (i < 4 ? r0 + i : 64 + r0 + (i - 4));
    if (row < n) {
      float rs = rsqrtf((float)(cnt[row] + 1));   // dis[row] pre-scale for aggregation
      float4 o0, o1;
      o0.x = (acc[i][0] + bb0[0]) * rs; o0.y = (acc[i][1] + bb0[1]) * rs;
      o0.z = (acc[i][2] + bb0[2]) * rs; o0.w = (acc[i][3] + bb0[3]) * rs;
      o1.x = (acc[i][4] + bb1[0]) * rs; o1.y = (acc[i][5] + bb1[1]) * rs;
      o1.z = (acc[i][6] + bb1[2]) * rs; o1.w = (acc[i][7] + bb1[3]) * rs;
      *(float4*)&out[(size_t)row * 128 + c0] = o0;
      *(float4*)&out[(size_t)row * 128 + 64 + c0] = o1;
    }
  }
}

// ---------------- aggregation (+ fused BN column stats) ----------------
__global__ __launch_bounds__(256) void agg_kernel(const float* __restrict__ z,
                                                  const int* __restrict__ cnt,
                                                  const int* __restrict__ csr,
                                                  float* __restrict__ out,
                                                  float* __restrict__ Ssum,
                                                  float* __restrict__ Ssq,
                                                  int n, int half) {
  __shared__ float bs[4][128], bq[4][128];
  int tid = threadIdx.x;
  int lane = tid & 63;
  int wv = tid >> 6;
  int w = (blockIdx.x * blockDim.x + tid) >> 6;
  float stx = 0.f, sty = 0.f, qtx = 0.f, qty = 0.f;
  if (w < half) {
    int i0 = w, i1 = w + half;
    bool has1 = (i1 < n);
    const float2* __restrict__ h2 = (const float2*)z;
    unsigned off0 = (unsigned)i0 * 64u + (unsigned)lane;
    unsigned off1 = (unsigned)i1 * 64u + (unsigned)lane;
    float2 self0 = h2[off0];
    float2 self1 = has1 ? h2[off1] : make_float2(0.f, 0.f);
    int c0r = cnt[i0];
    int c1r = has1 ? cnt[i1] : 0;
    float d0 = rsqrtf((float)(c0r + 1));
    float d1 = rsqrtf((float)(c1r + 1));
    int e0 = c0r > PAD ? PAD : c0r;
    int e1 = c1r > PAD ? PAD : c1r;
    const int* __restrict__ lp0 = csr + (size_t)i0 * PAD;
    const int* __restrict__ lp1 = csr + (size_t)i1 * PAD;
    float s0x = self0.x, s0y = self0.y;
    float s1x = self1.x, s1y = self1.y;
    int my0 = (lane < e0) ? lp0[lane] : 0;
    int my1 = (lane < e1) ? lp1[lane] : 0;
    int p0 = 0, p1 = 0;
    while (p0 + 8 <= e0 && p1 + 8 <= e1) {
      float2 v0[8], v1[8];
#pragma unroll
      for (int u = 0; u < 8; ++u) { int s = __shfl(my0, p0 + u, 64); v0[u] = h2[(unsigned)s * 64u + (unsigned)lane]; }
#pragma unroll
      for (int u = 0; u < 8; ++u) { int s = __shfl(my1, p1 + u, 64); v1[u] = h2[(unsigned)s * 64u + (unsigned)lane]; }
#pragma unroll
      for (int u = 0; u < 8; ++u) {
        s0x += v0[u].x; s0y += v0[u].y;
        s1x += v1[u].x; s1y += v1[u].y;
      }
      p0 += 8; p1 += 8;
    }
    for (; p0 + 8 <= e0; p0 += 8) {
      float2 v[8];
#pragma unroll
      for (int u = 0; u < 8; ++u) { int s = __shfl(my0, p0 + u, 64); v[u] = h2[(unsigned)s * 64u + (unsigned)lane]; }
#pragma unroll
      for (int u = 0; u < 8; ++u) { s0x += v[u].x; s0y += v[u].y; }
    }
    for (; p0 + 4 <= e0; p0 += 4) {
      float2 v[4];
#pragma unroll
      for (int u = 0; u < 4; ++u) { int s = __shfl(my0, p0 + u, 64); v[u] = h2[(unsigned)s * 64u + (unsigned)lane]; }
#pragma unroll
      for (int u = 0; u < 4; ++u) { s0x += v[u].x; s0y += v[u].y; }
    }
    for (; p0 < e0; ++p0) {
      int s = __shfl(my0, p0, 64);
      float2 v = h2[(unsigned)s * 64u + (unsigned)lane];
      s0x += v.x; s0y += v.y;
    }
    for (; p1 + 8 <= e1; p1 += 8) {
      float2 v[8];
#pragma unroll
      for (int u = 0; u < 8; ++u) { int s = __shfl(my1, p1 + u, 64); v[u] = h2[(unsigned)s * 64u + (unsigned)lane]; }
#pragma unroll
      for (int u = 0; u < 8; ++u) { s1x += v[u].x; s1y += v[u].y; }
    }
    for (; p1 + 4 <= e1; p1 += 4) {
      float2 v[4];
#pragma unroll
      for (int u = 0; u < 4; ++u) { int s = __shfl(my1, p1 + u, 64); v[u] = h2[(unsigned)s * 64u + (unsigned)lane]; }
#pragma unroll
      for (int u = 0; u < 4; ++u) { s1x += v[u].x; s1y += v[u].y; }
    }
    for (; p1 < e1; ++p1) {
      int s = __shfl(my1, p1, 64);
      float2 v = h2[(unsigned)s * 64u + (unsigned)lane];
      s1x += v.x; s1y += v.y;
    }
    float2 o0; o0.x = d0 * s0x; o0.y = d0 * s0y;
    ((float2*)out)[off0] = o0;
    stx += o0.x; qtx = fmaf(o0.x, o0.x, qtx);
    sty += o0.y; qty = fmaf(o0.y, o0.y, qty);
    if (has1) {
      float2 o1; o1.x = d1 * s1x; o1.y = d1 * s1y;
      ((float2*)out)[off1] = o1;
      stx += o1.x; qtx = fmaf(o1.x, o1.x, qtx);
      sty += o1.y; qty = fmaf(o1.y, o1.y, qty);
    }
  }
  bs[wv][2 * lane] = stx;     bs[wv][2 * lane + 1] = sty;
  bq[wv][2 * lane] = qtx;     bq[wv][2 * lane + 1] = qty;
  __syncthreads();
  if (tid < 128) {
    float s = bs[0][tid] + bs[1][tid] + bs[2][tid] + bs[3][tid];
    float q = bq[0][tid] + bq[1][tid] + bq[2][tid] + bq[3][tid];
    int slot = (blockIdx.x & (NSLOT - 1)) * 128 + tid;
    atomicAdd(&Ssum[slot], s);
    atomicAdd(&Ssq[slot], q);
  }
}

// ---------------- decoder: ypred[k] = leaky(BN(h[ia]))^T M leaky(BN(h[ib])) ----------------
__global__ __launch_bounds__(256) void decoder_kernel(
    const float* __restrict__ h, const int* __restrict__ di, const float* __restrict__ M,
    const float* __restrict__ bn_sum, const float* __restrict__ bn_sq,
    const float* __restrict__ bn_g, const float* __restrict__ bn_b,
    float* __restrict__ out, int npairs, int n, float invN) {
  __shared__ float Ms[128 * 128];
  __shared__ float sc[128], sh[128];
  int tid = threadIdx.x;
  if (tid < 128) {
    float s = 0.f, q = 0.f;
    for (int r2 = 0; r2 < NSLOT; ++r2) { s += bn_sum[r2 * 128 + tid]; q += bn_sq[r2 * 128 + tid]; }
    float m = s * invN;
    float var = q * invN - m * m;
    float rs = rsqrtf(var + 1e-5f);
    float scv = rs * bn_g[tid];
    sc[tid] = scv;
    sh[tid] = bn_b[tid] - m * scv;
  }
  for (int t = tid; t < 4096; t += 256) ((float4*)Ms)[t] = ((const float4*)M)[t];
  __syncthreads();
  int lane = tid & 63, wv = tid >> 6;
  int wid = blockIdx.x * 4 + wv;
  int nw = gridDim.x * 4;
  for (int k = wid; k < npairs; k += nw) {
    int ia = di[2 * k] - 1;     if (ia < 0) ia += n;
    int ib = di[2 * k + 1] - 1; if (ib < 0) ib += n;
    const float2* ap2 = (const float2*)(h + (size_t)ia * 128);
    const float* bp = h + (size_t)ib * 128;
    float2 a2 = ap2[lane];
    float ax = a2.x * sc[2 * lane] + sh[2 * lane];         ax = ax >= 0.f ? ax : 0.1f * ax;
    float ay = a2.y * sc[2 * lane + 1] + sh[2 * lane + 1]; ay = ay >= 0.f ? ay : 0.1f * ay;
    float u0 = 0.f, u1 = 0.f;
#pragma unroll 8
    for (int i2 = 0; i2 < 64; ++i2) {
      float avx = __shfl(ax, i2, 64);
      float avy = __shfl(ay, i2, 64);
      int i = 2 * i2;
      u0 = fmaf(avx, Ms[i * 128 + lane], u0);
      u1 = fmaf(avx, Ms[i * 128 + 64 + lane], u1);
      u0 = fmaf(avy, Ms[(i + 1) * 128 + lane], u0);
      u1 = fmaf(avy, Ms[(i + 1) * 128 + 64 + lane], u1);
    }
    float b0 = bp[lane] * sc[lane] + sh[lane];                b0 = b0 >= 0.f ? b0 : 0.1f * b0;
    float b1 = bp[lane + 64] * sc[lane + 64] + sh[lane + 64]; b1 = b1 >= 0.f ? b1 : 0.1f * b1;
    float part = u0 * b0 + u1 * b1;
#pragma unroll
    for (int o = 32; o; o >>= 1) part += __shfl_down(part, o, 64);
    if (lane == 0) out[k] = part;
  }
}

extern "C" void kernel_launch(void* const* d_in, const int* in_sizes, int n_in,
                              void* d_out, int out_size, void* d_ws, size_t ws_size,
                              hipStream_t stream) {
  const float* x   = (const float*)d_in[0];
  const int*   ei  = (const int*)d_in[1];
  const int*   dri = (const int*)d_in[2];
  const float* w1  = (const float*)d_in[3];
  const float* b1  = (const float*)d_in[4];
  const float* w2  = (const float*)d_in[5];
  const float* b2  = (const float*)d_in[6];
  const float* w3  = (const float*)d_in[7];
  const float* b3  = (const float*)d_in[8];
  const float* g1  = (const float*)d_in[9];
  const float* be1 = (const float*)d_in[10];
  const float* g2  = (const float*)d_in[11];
  const float* be2 = (const float*)d_in[12];
  const float* g3  = (const float*)d_in[13];
  const float* be3 = (const float*)d_in[14];
  const float* p1  = (const float*)d_in[15];
  const float* p2  = (const float*)d_in[16];
  float* out = (float*)d_out;

  int n  = in_sizes[0] / 128;
  int ne = in_sizes[1] / 2;
  int np = in_sizes[2] / 2;
  const int* erow = ei;
  const int* ecol = ei + ne;

  size_t o = 0;
  char* wsb = (char*)d_ws;
  auto alloc = [&](size_t bytes) { void* p = wsb + o; o += (bytes + 255) & ~255ull; return p; };
  float* T1   = (float*)alloc((size_t)n * 128 * 4);
  float* T2   = (float*)alloc((size_t)n * 128 * 4);
  int*   csr  = (int*)alloc((size_t)n * PAD * 4);
  int*   cnt  = (int*)alloc((size_t)n * 4);
  int nstat = 6 * NSLOT * 128;
  float* stats = (float*)alloc((size_t)nstat * 4);
  float* M2   = (float*)alloc(128 * 128 * 4);
  float* Ssum1 = stats;
  float* Ssq1  = stats + 1 * NSLOT * 128;
  float* Ssum2 = stats + 2 * NSLOT * 128;
  float* Ssq2  = stats + 3 * NSLOT * 128;
  float* Ssum3 = stats + 4 * NSLOT * 128;
  float* Ssq3  = stats + 5 * NSLOT * 128;

  float invN = 1.0f / (float)n;
  int eb = (ne + 255) / 256;
  int gb = (n + 127) / 128;
  int half = (n + 1) / 2;
  int ab = (half + 3) / 4;

  init_kernel<<<257, 256, 0, stream>>>(cnt, stats, n, nstat, p1, p2, M2);
  fillcsr_kernel<<<eb, 256, 0, stream>>>(erow, ecol, cnt, csr, ne);

  // layer 1
  gemm_kernel<<<gb, 256, 0, stream>>>(x, w1, b1, T1, n, invN, nullptr, nullptr, nullptr, nullptr, 0, cnt);
  agg_kernel<<<ab, 256, 0, stream>>>(T1, cnt, csr, T2, Ssum1, Ssq1, n, half);

  // layer 2 (BN1+leaky fused into loader)
  gemm_kernel<<<gb, 256, 0, stream>>>(T2, w2, b2, T1, n, invN, Ssum1, Ssq1, g1, be1, 1, cnt);
  agg_kernel<<<ab, 256, 0, stream>>>(T1, cnt, csr, T2, Ssum2, Ssq2, n, half);

  // layer 3 (BN2+leaky fused into loader)
  gemm_kernel<<<gb, 256, 0, stream>>>(T2, w3, b3, T1, n, invN, Ssum2, Ssq2, g2, be2, 1, cnt);
  agg_kernel<<<ab, 256, 0, stream>>>(T1, cnt, csr, T2, Ssum3, Ssq3, n, half);

  // decoder (M2 precomputed in init)
  decoder_kernel<<<256, 256, 0, stream>>>(T2, dri, M2, Ssum3, Ssq3, g3, be3, out, np, n, invN);
}

// Round 13
// 361.905 us; speedup vs baseline: 2.2945x; 2.2945x over previous
//
#include <hip/hip_runtime.h>

#define PAD 64
#define NSLOT 64   // stats scatter slots (contention spreading)

// ---------------- init: zero cnt ----------------
__global__ void init_kernel(int* __restrict__ cnt, int n) {
  int i = blockIdx.x * blockDim.x + threadIdx.x;
  int stride = gridDim.x * blockDim.x;
  for (int j = i; j < n; j += stride) cnt[j] = 0;
}

// ---------------- fused degree count + padded-CSR fill (+ stats zeroing) ----------------
__global__ void fillcsr_kernel(const int* __restrict__ row, const int* __restrict__ col,
                               int* __restrict__ cnt, int* __restrict__ csr, int ne,
                               float* __restrict__ stats, int nstat) {
  int gid = blockIdx.x * blockDim.x + threadIdx.x;
  int stride = gridDim.x * blockDim.x;
  for (int j = gid; j < nstat; j += stride) stats[j] = 0.f;
  if (gid < ne) {
    int d = col[gid];
    int p = atomicAdd(&cnt[d], 1);
    if (p < PAD) csr[d * PAD + p] = row[gid];
  }
}

// ---------------- GEMM: out[row] = dis[row] * ( leaky(BN(A[row])) @ W + b ) ----------------
// K-paneled (4 panels of 32): 33 KB LDS -> 4 blocks/CU. k-major A panel, ds_read_b128 inner loop.
// Blocks >= gb run a small bilinear side-job (bilin_mode 1: Mo=P@Q ; 2: Mo[i,j]=sum_l P[i,l]Q[j,l]).
__global__ __launch_bounds__(256, 4) void gemm_kernel(
    const float* __restrict__ A, const float* __restrict__ W, const float* __restrict__ bias,
    float* __restrict__ out, int n, float invN,
    const float* __restrict__ bn_sum, const float* __restrict__ bn_sq,
    const float* __restrict__ bn_g, const float* __restrict__ bn_b, int use_bn,
    const int* __restrict__ cnt, int gb,
    const float* __restrict__ P, const float* __restrict__ Q, float* __restrict__ Mo,
    int bilin_mode) {
  __shared__ float Ws[32 * 128];    // Ws[k][col], k local to panel
  __shared__ float xs[32 * 128];    // xs[k][row], k local to panel
  __shared__ float bnsc[128], bnsh[128];
  int tid = threadIdx.x;

  if ((int)blockIdx.x >= gb) {
    // ---- bilinear side-job: one output row per block, wide-parallel, tiny LDS use ----
    int i = blockIdx.x - gb;
    if (tid < 128) bnsc[tid] = P[i * 128 + tid];
    __syncthreads();
    int j = tid & 127, kh = tid >> 7;
    float acc = 0.f;
    if (bilin_mode == 1) {
      for (int k = kh * 64; k < kh * 64 + 64; ++k) acc = fmaf(bnsc[k], Q[k * 128 + j], acc);
    } else {
      const float* qr = Q + (size_t)j * 128;
      for (int l = kh * 64; l < kh * 64 + 64; ++l) acc = fmaf(bnsc[l], qr[l], acc);
    }
    xs[tid] = acc;
    __syncthreads();
    if (tid < 128) Mo[i * 128 + tid] = xs[tid] + xs[128 + tid];
    return;
  }

  if (tid < 128) {
    if (use_bn) {
      float s = 0.f, q = 0.f;
      for (int r2 = 0; r2 < NSLOT; ++r2) { s += bn_sum[r2 * 128 + tid]; q += bn_sq[r2 * 128 + tid]; }
      float m = s * invN;
      float var = q * invN - m * m;
      float rs = rsqrtf(var + 1e-5f);
      float sc = rs * bn_g[tid];
      bnsc[tid] = sc;
      bnsh[tid] = bn_b[tid] - m * sc;
    } else {
      bnsc[tid] = 1.f; bnsh[tid] = 0.f;
    }
  }
  int base = blockIdx.x * 128;
  int tx = tid & 15, ty = tid >> 4;
  int c0 = tx * 4, r0 = ty * 4;
  int r = tid & 127;            // staging row
  int row_s = base + r;
  int hf = tid >> 7;            // 0/1
  int kw = tid >> 5;            // 0..7 (W staging k)
  int c4 = tid & 31;            // W staging col4
  const float4* Arow = (const float4*)(A + (size_t)row_s * 128);
  float acc[8][8];
#pragma unroll
  for (int i = 0; i < 8; ++i)
#pragma unroll
    for (int j = 0; j < 8; ++j) acc[i][j] = 0.f;

  for (int kp = 0; kp < 4; ++kp) {
    __syncthreads();
#pragma unroll
    for (int it = 0; it < 4; ++it) {
      int kl = kw + it * 8;
      float4 wv = ((const float4*)(W + (size_t)(kp * 32 + kl) * 128))[c4];
      *(float4*)&Ws[kl * 128 + c4 * 4] = wv;
    }
#pragma unroll
    for (int it = 0; it < 4; ++it) {
      int kbl = hf + it * 2;
      float4 v = make_float4(0.f, 0.f, 0.f, 0.f);
      if (row_s < n) v = Arow[kp * 8 + kbl];
      if (use_bn) {
        int k0 = kp * 32 + kbl * 4;
        float t;
        t = v.x * bnsc[k0 + 0] + bnsh[k0 + 0]; v.x = t >= 0.f ? t : 0.1f * t;
        t = v.y * bnsc[k0 + 1] + bnsh[k0 + 1]; v.y = t >= 0.f ? t : 0.1f * t;
        t = v.z * bnsc[k0 + 2] + bnsh[k0 + 2]; v.z = t >= 0.f ? t : 0.1f * t;
        t = v.w * bnsc[k0 + 3] + bnsh[k0 + 3]; v.w = t >= 0.f ? t : 0.1f * t;
      }
      int kl = kbl * 4;
      xs[(kl + 0) * 128 + r] = v.x;
      xs[(kl + 1) * 128 + r] = v.y;
      xs[(kl + 2) * 128 + r] = v.z;
      xs[(kl + 3) * 128 + r] = v.w;
    }
    __syncthreads();
#pragma unroll 4
    for (int k = 0; k < 32; ++k) {
      float4 a0 = *(const float4*)&xs[k * 128 + r0];
      float4 a1 = *(const float4*)&xs[k * 128 + 64 + r0];
      float4 w0 = *(const float4*)&Ws[k * 128 + c0];
      float4 w1 = *(const float4*)&Ws[k * 128 + 64 + c0];
      float xr[8], wc[8];
      xr[0] = a0.x; xr[1] = a0.y; xr[2] = a0.z; xr[3] = a0.w;
      xr[4] = a1.x; xr[5] = a1.y; xr[6] = a1.z; xr[7] = a1.w;
      wc[0] = w0.x; wc[1] = w0.y; wc[2] = w0.z; wc[3] = w0.w;
      wc[4] = w1.x; wc[5] = w1.y; wc[6] = w1.z; wc[7] = w1.w;
#pragma unroll
      for (int i = 0; i < 8; ++i)
#pragma unroll
        for (int j = 0; j < 8; ++j)
          acc[i][j] = fmaf(xr[i], wc[j], acc[i][j]);
    }
  }
  float bb0[4], bb1[4];
#pragma unroll
  for (int j = 0; j < 4; ++j) { bb0[j] = bias[c0 + j]; bb1[j] = bias[64 + c0 + j]; }
#pragma unroll
  for (int i = 0; i < 8; ++i) {
    int row = base + (i < 4 ? r0 + i : 64 + r0 + (i - 4));
    if (row < n) {
      float rs = rsqrtf((float)(cnt[row] + 1));   // dis[row] pre-scale for aggregation
      float4 o0, o1;
      o0.x = (acc[i][0] + bb0[0]) * rs; o0.y = (acc[i][1] + bb0[1]) * rs;
      o0.z = (acc[i][2] + bb0[2]) * rs; o0.w = (acc[i][3] + bb0[3]) * rs;
      o1.x = (acc[i][4] + bb1[0]) * rs; o1.y = (acc[i][5] + bb1[1]) * rs;
      o1.z = (acc[i][6] + bb1[2]) * rs; o1.w = (acc[i][7] + bb1[3]) * rs;
      *(float4*)&out[(size_t)row * 128 + c0] = o0;
      *(float4*)&out[(size_t)row * 128 + 64 + c0] = o1;
    }
  }
}

// ---------------- aggregation (+ fused BN column stats) ----------------
__global__ __launch_bounds__(256) void agg_kernel(const float* __restrict__ z,
                                                  const int* __restrict__ cnt,
                                                  const int* __restrict__ csr,
                                                  float* __restrict__ out,
                                                  float* __restrict__ Ssum,
                                                  float* __restrict__ Ssq,
                                                  int n, int half) {
  __shared__ float bs[4][128], bq[4][128];
  int tid = threadIdx.x;
  int lane = tid & 63;
  int wv = tid >> 6;
  int w = (blockIdx.x * blockDim.x + tid) >> 6;
  float stx = 0.f, sty = 0.f, qtx = 0.f, qty = 0.f;
  if (w < half) {
    int i0 = w, i1 = w + half;
    bool has1 = (i1 < n);
    const float2* __restrict__ h2 = (const float2*)z;
    unsigned off0 = (unsigned)i0 * 64u + (unsigned)lane;
    unsigned off1 = (unsigned)i1 * 64u + (unsigned)lane;
    float2 self0 = h2[off0];
    float2 self1 = has1 ? h2[off1] : make_float2(0.f, 0.f);
    int c0r = cnt[i0];
    int c1r = has1 ? cnt[i1] : 0;
    float d0 = rsqrtf((float)(c0r + 1));
    float d1 = rsqrtf((float)(c1r + 1));
    int e0 = c0r > PAD ? PAD : c0r;
    int e1 = c1r > PAD ? PAD : c1r;
    const int* __restrict__ lp0 = csr + (size_t)i0 * PAD;
    const int* __restrict__ lp1 = csr + (size_t)i1 * PAD;
    float s0x = self0.x, s0y = self0.y;
    float s1x = self1.x, s1y = self1.y;
    int my0 = (lane < e0) ? lp0[lane] : 0;
    int my1 = (lane < e1) ? lp1[lane] : 0;
    int p0 = 0, p1 = 0;
    while (p0 + 8 <= e0 && p1 + 8 <= e1) {
      float2 v0[8], v1[8];
#pragma unroll
      for (int u = 0; u < 8; ++u) { int s = __shfl(my0, p0 + u, 64); v0[u] = h2[(unsigned)s * 64u + (unsigned)lane]; }
#pragma unroll
      for (int u = 0; u < 8; ++u) { int s = __shfl(my1, p1 + u, 64); v1[u] = h2[(unsigned)s * 64u + (unsigned)lane]; }
#pragma unroll
      for (int u = 0; u < 8; ++u) {
        s0x += v0[u].x; s0y += v0[u].y;
        s1x += v1[u].x; s1y += v1[u].y;
      }
      p0 += 8; p1 += 8;
    }
    for (; p0 + 8 <= e0; p0 += 8) {
      float2 v[8];
#pragma unroll
      for (int u = 0; u < 8; ++u) { int s = __shfl(my0, p0 + u, 64); v[u] = h2[(unsigned)s * 64u + (unsigned)lane]; }
#pragma unroll
      for (int u = 0; u < 8; ++u) { s0x += v[u].x; s0y += v[u].y; }
    }
    for (; p0 + 4 <= e0; p0 += 4) {
      float2 v[4];
#pragma unroll
      for (int u = 0; u < 4; ++u) { int s = __shfl(my0, p0 + u, 64); v[u] = h2[(unsigned)s * 64u + (unsigned)lane]; }
#pragma unroll
      for (int u = 0; u < 4; ++u) { s0x += v[u].x; s0y += v[u].y; }
    }
    for (; p0 < e0; ++p0) {
      int s = __shfl(my0, p0, 64);
      float2 v = h2[(unsigned)s * 64u + (unsigned)lane];
      s0x += v.x; s0y += v.y;
    }
    for (; p1 + 8 <= e1; p1 += 8) {
      float2 v[8];
#pragma unroll
      for (int u = 0; u < 8; ++u) { int s = __shfl(my1, p1 + u, 64); v[u] = h2[(unsigned)s * 64u + (unsigned)lane]; }
#pragma unroll
      for (int u = 0; u < 8; ++u) { s1x += v[u].x; s1y += v[u].y; }
    }
    for (; p1 + 4 <= e1; p1 += 4) {
      float2 v[4];
#pragma unroll
      for (int u = 0; u < 4; ++u) { int s = __shfl(my1, p1 + u, 64); v[u] = h2[(unsigned)s * 64u + (unsigned)lane]; }
#pragma unroll
      for (int u = 0; u < 4; ++u) { s1x += v[u].x; s1y += v[u].y; }
    }
    for (; p1 < e1; ++p1) {
      int s = __shfl(my1, p1, 64);
      float2 v = h2[(unsigned)s * 64u + (unsigned)lane];
      s1x += v.x; s1y += v.y;
    }
    float2 o0; o0.x = d0 * s0x; o0.y = d0 * s0y;
    ((float2*)out)[off0] = o0;
    stx += o0.x; qtx = fmaf(o0.x, o0.x, qtx);
    sty += o0.y; qty = fmaf(o0.y, o0.y, qty);
    if (has1) {
      float2 o1; o1.x = d1 * s1x; o1.y = d1 * s1y;
      ((float2*)out)[off1] = o1;
      stx += o1.x; qtx = fmaf(o1.x, o1.x, qtx);
      sty += o1.y; qty = fmaf(o1.y, o1.y, qty);
    }
  }
  bs[wv][2 * lane] = stx;     bs[wv][2 * lane + 1] = sty;
  bq[wv][2 * lane] = qtx;     bq[wv][2 * lane + 1] = qty;
  __syncthreads();
  if (tid < 128) {
    float s = bs[0][tid] + bs[1][tid] + bs[2][tid] + bs[3][tid];
    float q = bq[0][tid] + bq[1][tid] + bq[2][tid] + bq[3][tid];
    int slot = (blockIdx.x & (NSLOT - 1)) * 128 + tid;
    atomicAdd(&Ssum[slot], s);
    atomicAdd(&Ssq[slot], q);
  }
}

// ---------------- decoder: ypred[k] = leaky(BN(h[ia]))^T M leaky(BN(h[ib])) ----------------
__global__ __launch_bounds__(256) void decoder_kernel(
    const float* __restrict__ h, const int* __restrict__ di, const float* __restrict__ M,
    const float* __restrict__ bn_sum, const float* __restrict__ bn_sq,
    const float* __restrict__ bn_g, const float* __restrict__ bn_b,
    float* __restrict__ out, int npairs, int n, float invN) {
  __shared__ float Ms[128 * 128];
  __shared__ float sc[128], sh[128];
  int tid = threadIdx.x;
  if (tid < 128) {
    float s = 0.f, q = 0.f;
    for (int r2 = 0; r2 < NSLOT; ++r2) { s += bn_sum[r2 * 128 + tid]; q += bn_sq[r2 * 128 + tid]; }
    float m = s * invN;
    float var = q * invN - m * m;
    float rs = rsqrtf(var + 1e-5f);
    float scv = rs * bn_g[tid];
    sc[tid] = scv;
    sh[tid] = bn_b[tid] - m * scv;
  }
  for (int t = tid; t < 4096; t += 256) ((float4*)Ms)[t] = ((const float4*)M)[t];
  __syncthreads();
  int lane = tid & 63, wv = tid >> 6;
  int wid = blockIdx.x * 4 + wv;
  int nw = gridDim.x * 4;
  for (int k = wid; k < npairs; k += nw) {
    int ia = di[2 * k] - 1;     if (ia < 0) ia += n;
    int ib = di[2 * k + 1] - 1; if (ib < 0) ib += n;
    const float2* ap2 = (const float2*)(h + (size_t)ia * 128);
    const float* bp = h + (size_t)ib * 128;
    float2 a2 = ap2[lane];
    float ax = a2.x * sc[2 * lane] + sh[2 * lane];         ax = ax >= 0.f ? ax : 0.1f * ax;
    float ay = a2.y * sc[2 * lane + 1] + sh[2 * lane + 1]; ay = ay >= 0.f ? ay : 0.1f * ay;
    float u0 = 0.f, u1 = 0.f;
#pragma unroll 8
    for (int i2 = 0; i2 < 64; ++i2) {
      float avx = __shfl(ax, i2, 64);
      float avy = __shfl(ay, i2, 64);
      int i = 2 * i2;
      u0 = fmaf(avx, Ms[i * 128 + lane], u0);
      u1 = fmaf(avx, Ms[i * 128 + 64 + lane], u1);
      u0 = fmaf(avy, Ms[(i + 1) * 128 + lane], u0);
      u1 = fmaf(avy, Ms[(i + 1) * 128 + 64 + lane], u1);
    }
    float b0 = bp[lane] * sc[lane] + sh[lane];                b0 = b0 >= 0.f ? b0 : 0.1f * b0;
    float b1 = bp[lane + 64] * sc[lane + 64] + sh[lane + 64]; b1 = b1 >= 0.f ? b1 : 0.1f * b1;
    float part = u0 * b0 + u1 * b1;
#pragma unroll
    for (int o = 32; o; o >>= 1) part += __shfl_down(part, o, 64);
    if (lane == 0) out[k] = part;
  }
}

extern "C" void kernel_launch(void* const* d_in, const int* in_sizes, int n_in,
                              void* d_out, int out_size, void* d_ws, size_t ws_size,
                              hipStream_t stream) {
  const float* x   = (const float*)d_in[0];
  const int*   ei  = (const int*)d_in[1];
  const int*   dri = (const int*)d_in[2];
  const float* w1  = (const float*)d_in[3];
  const float* b1  = (const float*)d_in[4];
  const float* w2  = (const float*)d_in[5];
  const float* b2  = (const float*)d_in[6];
  const float* w3  = (const float*)d_in[7];
  const float* b3  = (const float*)d_in[8];
  const float* g1  = (const float*)d_in[9];
  const float* be1 = (const float*)d_in[10];
  const float* g2  = (const float*)d_in[11];
  const float* be2 = (const float*)d_in[12];
  const float* g3  = (const float*)d_in[13];
  const float* be3 = (const float*)d_in[14];
  const float* p1  = (const float*)d_in[15];
  const float* p2  = (const float*)d_in[16];
  float* out = (float*)d_out;

  int n  = in_sizes[0] / 128;
  int ne = in_sizes[1] / 2;
  int np = in_sizes[2] / 2;
  const int* erow = ei;
  const int* ecol = ei + ne;

  size_t o = 0;
  char* wsb = (char*)d_ws;
  auto alloc = [&](size_t bytes) { void* p = wsb + o; o += (bytes + 255) & ~255ull; return p; };
  float* T1   = (float*)alloc((size_t)n * 128 * 4);
  float* T2   = (float*)alloc((size_t)n * 128 * 4);
  int*   csr  = (int*)alloc((size_t)n * PAD * 4);
  int*   cnt  = (int*)alloc((size_t)n * 4);
  int nstat = 6 * NSLOT * 128;
  float* stats = (float*)alloc((size_t)nstat * 4);
  float* Mtmp = (float*)alloc(128 * 128 * 4);
  float* M2   = (float*)alloc(128 * 128 * 4);
  float* Ssum1 = stats;
  float* Ssq1  = stats + 1 * NSLOT * 128;
  float* Ssum2 = stats + 2 * NSLOT * 128;
  float* Ssq2  = stats + 3 * NSLOT * 128;
  float* Ssum3 = stats + 4 * NSLOT * 128;
  float* Ssq3  = stats + 5 * NSLOT * 128;

  float invN = 1.0f / (float)n;
  int eb = (ne + 255) / 256;
  int gb = (n + 127) / 128;
  int half = (n + 1) / 2;
  int ab = (half + 3) / 4;

  init_kernel<<<256, 256, 0, stream>>>(cnt, n);
  fillcsr_kernel<<<eb, 256, 0, stream>>>(erow, ecol, cnt, csr, ne, stats, nstat);

  // layer 1 (+128 side blocks: Mtmp = p1 @ p2)
  gemm_kernel<<<gb + 128, 256, 0, stream>>>(x, w1, b1, T1, n, invN,
                                            nullptr, nullptr, nullptr, nullptr, 0, cnt,
                                            gb, p1, p2, Mtmp, 1);
  agg_kernel<<<ab, 256, 0, stream>>>(T1, cnt, csr, T2, Ssum1, Ssq1, n, half);

  // layer 2 (BN1) (+128 side blocks: M2 = Mtmp @ p1^T)
  gemm_kernel<<<gb + 128, 256, 0, stream>>>(T2, w2, b2, T1, n, invN,
                                            Ssum1, Ssq1, g1, be1, 1, cnt,
                                            gb, Mtmp, p1, M2, 2);
  agg_kernel<<<ab, 256, 0, stream>>>(T1, cnt, csr, T2, Ssum2, Ssq2, n, half);

  // layer 3 (BN2)
  gemm_kernel<<<gb, 256, 0, stream>>>(T2, w3, b3, T1, n, invN,
                                      Ssum2, Ssq2, g2, be2, 1, cnt,
                                      gb, nullptr, nullptr, nullptr, 0);
  agg_kernel<<<ab, 256, 0, stream>>>(T1, cnt, csr, T2, Ssum3, Ssq3, n, half);

  // decoder (M2 computed by gemm2's side blocks)
  decoder_kernel<<<256, 256, 0, stream>>>(T2, dri, M2, Ssum3, Ssq3, g3, be3, out, np, n, invN);
}